// Round 13
// baseline (69.463 us; speedup 1.0000x reference)
//
#include <hip/hip_runtime.h>

#define B 4
#define NQ 512
#define NK 512
#define D 128
#define H 32
#define G 4                              // queries per attend block
#define PS 2.8853900817779268f           // 2*log2(e)
#define NBLOCKS 512

__device__ __forceinline__ float rcp_f(float x)  { return __builtin_amdgcn_rcpf(x); }
__device__ __forceinline__ float exp2_f(float x) { return __builtin_amdgcn_exp2f(x); }

__device__ __forceinline__ void fma4(float4& a, const float4& v, float s) {
    a.x = fmaf(s, v.x, a.x);
    a.y = fmaf(s, v.y, a.y);
    a.z = fmaf(s, v.z, a.z);
    a.w = fmaf(s, v.w, a.w);
}

// Single fused kernel. Phase A: this block's 8 projection rows -> Ek/eq.
// Grid barrier (all 512 blocks co-resident: 3 blocks/CU capacity, 40KB LDS).
// Phase 1/2: r11 attend body, byte-identical math.
__global__ __launch_bounds__(512, 6) void fused_kernel(
    const float* __restrict__ keys, const float* __restrict__ queries,
    const float* __restrict__ Wk, const float* __restrict__ Wq,
    const float* __restrict__ b1, const float* __restrict__ w2,
    float* __restrict__ Ek,       // [B][H][NK] ws
    float* __restrict__ eq,       // [B][NQ][H] ws
    unsigned int* __restrict__ ctr,
    float* __restrict__ outp)
{
    __shared__ float exw[NK][G];      // 8 KB   normalized weights
    __shared__ float accm[16][G][D];  // 32 KB  ph2 partials; start doubles as
                                      //        xs[8][D] (ph A) and red[8][G] (ph 1)
    float* xs  = &accm[0][0][0];
    float* red = &accm[0][0][0];

    const int tid = threadIdx.x;
    const int bid = blockIdx.x;

    // ================= phase A: projection of rows [bid*8, bid*8+8) =========
    {
        const int r0 = bid * 8;
        const bool is_q = (r0 >= B * NK);
        const float* __restrict__ X = is_q ? (queries + (size_t)(r0 - B * NK) * D)
                                           : (keys + (size_t)r0 * D);
        const float* __restrict__ W = is_q ? Wq : Wk;
        if (tid < 256)
            reinterpret_cast<float4*>(xs)[tid] = reinterpret_cast<const float4*>(X)[tid];
        __syncthreads();

        const int task = tid >> 1;    // 0..255 = (lr, h)
        const int half = tid & 1;     // d-half
        const int lr = task >> 5;
        const int h  = task & 31;
        float a0 = 0.f, a1 = 0.f, a2 = 0.f, a3 = 0.f;
        const float4* x4 = reinterpret_cast<const float4*>(xs + lr * D) + half * 16;
        const float* Wb = W + (half * 64) * H + h;
        #pragma unroll
        for (int i = 0; i < 16; ++i) {
            float4 v = x4[i];
            a0 = fmaf(v.x, Wb[(4 * i + 0) * H], a0);
            a1 = fmaf(v.y, Wb[(4 * i + 1) * H], a1);
            a2 = fmaf(v.z, Wb[(4 * i + 2) * H], a2);
            a3 = fmaf(v.w, Wb[(4 * i + 3) * H], a3);
        }
        float acc = (a0 + a1) + (a2 + a3);
        acc += __shfl_xor(acc, 1);    // combine d-halves (lanes 2t, 2t+1)
        if (half == 0) {
            if (is_q) {
                const int rq = r0 - B * NK + lr;
                eq[(size_t)rq * H + h] = exp2_f(acc * PS);
            } else {
                const int r  = r0 + lr;
                const int bb = r >> 9;
                const int k  = r & (NK - 1);
                Ek[((size_t)bb * H + h) * NK + k] = exp2_f((acc + b1[h]) * PS);
            }
        }
    }
    __syncthreads();                  // drains all phase-A stores (vmcnt 0)

    // ================= grid barrier (device-scope, XCD-safe) ================
    if (tid == 0) {
        __threadfence();              // flush L2 -> LLC (release)
        __hip_atomic_fetch_add(ctr, 1u, __ATOMIC_RELAXED, __HIP_MEMORY_SCOPE_AGENT);
        while (__hip_atomic_load(ctr, __ATOMIC_RELAXED, __HIP_MEMORY_SCOPE_AGENT) < NBLOCKS)
            __builtin_amdgcn_s_sleep(1);
        __threadfence();              // invalidate stale L2 (acquire)
    }
    __syncthreads();

    // ================= phase 1: logits for key k = tid, queries q0..q0+3 ====
    const int b  = bid >> 7;
    const int q0 = (bid & 127) * G;

    float acc[G];
    #pragma unroll
    for (int g = 0; g < G; ++g) acc[g] = 0.f;
    const float* Ekc = Ek + (size_t)b * H * NK + tid;      // column base (per-lane)
    const float* eqb = eq + ((size_t)b * NQ + q0) * H;     // uniform -> s_load

    #pragma unroll
    for (int h4 = 0; h4 < H; h4 += 4) {
        const float ek0 = Ekc[(h4 + 0) * NK];   // coalesced 256B wave loads
        const float ek1 = Ekc[(h4 + 1) * NK];
        const float ek2 = Ekc[(h4 + 2) * NK];
        const float ek3 = Ekc[(h4 + 3) * NK];
        const float w0 = w2[h4 + 0];            // scalar loads
        const float w1 = w2[h4 + 1];
        const float wc = w2[h4 + 2];
        const float w3 = w2[h4 + 3];
        #pragma unroll
        for (int g = 0; g < G; ++g) {
            const float d0 = fmaf(eqb[g * H + h4 + 0], ek0, 1.f);
            const float d1 = fmaf(eqb[g * H + h4 + 1], ek1, 1.f);
            const float d2 = fmaf(eqb[g * H + h4 + 2], ek2, 1.f);
            const float d3 = fmaf(eqb[g * H + h4 + 3], ek3, 1.f);
            const float nab = fmaf(w1, d0, w0 * d1);
            const float ncd = fmaf(w3, d2, wc * d3);
            const float dab = d0 * d1;
            const float dcd = d2 * d3;
            const float n4  = fmaf(nab, dcd, ncd * dab);
            const float d4  = dab * dcd;
            acc[g] = fmaf(n4, rcp_f(d4), acc[g]);      // ONE rcp per 4 h's
        }
    }
    // exponent = -PS*acc (const dropped; |exponent| <= 16.3 -> no max pass)
    float e0 = exp2_f(-PS * acc[0]);
    float e1 = exp2_f(-PS * acc[1]);
    float e2 = exp2_f(-PS * acc[2]);
    float e3 = exp2_f(-PS * acc[3]);

    // block sum over k (red aliases accm; xs dead)
    float s0 = e0, s1 = e1, s2 = e2, s3 = e3;
    #pragma unroll
    for (int off = 32; off; off >>= 1) {
        s0 += __shfl_xor(s0, off);
        s1 += __shfl_xor(s1, off);
        s2 += __shfl_xor(s2, off);
        s3 += __shfl_xor(s3, off);
    }
    if ((tid & 63) == 0)
        *reinterpret_cast<float4*>(red + (tid >> 6) * G) = float4{s0, s1, s2, s3};
    __syncthreads();
    float4 sum = {0.f, 0.f, 0.f, 0.f};
    #pragma unroll
    for (int p = 0; p < 8; ++p) {
        const float4 v = *reinterpret_cast<const float4*>(red + p * G);
        sum.x += v.x; sum.y += v.y; sum.z += v.z; sum.w += v.w;
    }
    *reinterpret_cast<float4*>(&exw[tid][0]) =
        float4{e0 * rcp_f(sum.x), e1 * rcp_f(sum.y),
               e2 * rcp_f(sum.z), e3 * rcp_f(sum.w)};
    __syncthreads();                  // red reads done -> accm reusable

    // ================= phase 2: context =====================================
    const int dg = tid & 31;
    const int kp = tid >> 5;
    const float4* k4 = reinterpret_cast<const float4*>(
        keys + ((size_t)b * NK + kp * 32) * D) + dg;
    float4 a0 = {0,0,0,0}, a1 = a0, a2 = a0, a3 = a0;
    #pragma unroll 8
    for (int kk = 0; kk < 32; ++kk) {
        const float4 ev = *reinterpret_cast<const float4*>(&exw[kp * 32 + kk][0]);
        const float4 kv = k4[(size_t)kk * (D / 4)];
        fma4(a0, kv, ev.x);
        fma4(a1, kv, ev.y);
        fma4(a2, kv, ev.z);
        fma4(a3, kv, ev.w);
    }
    *reinterpret_cast<float4*>(&accm[kp][0][4 * dg]) = a0;
    *reinterpret_cast<float4*>(&accm[kp][1][4 * dg]) = a1;
    *reinterpret_cast<float4*>(&accm[kp][2][4 * dg]) = a2;
    *reinterpret_cast<float4*>(&accm[kp][3][4 * dg]) = a3;
    __syncthreads();

    const int g = tid >> 7;
    const int d = tid & 127;
    float r = 0.f;
    #pragma unroll
    for (int p = 0; p < 16; ++p) r += accm[p][g][d];
    outp[((size_t)b * NQ + q0 + g) * D + d] = r;
}

extern "C" void kernel_launch(void* const* d_in, const int* in_sizes, int n_in,
                              void* d_out, int out_size, void* d_ws, size_t ws_size,
                              hipStream_t stream) {
    const float* keys    = (const float*)d_in[0];
    const float* queries = (const float*)d_in[1];
    const float* Wk      = (const float*)d_in[2];
    const float* Wq      = (const float*)d_in[3];
    const float* b1      = (const float*)d_in[4];
    const float* w2      = (const float*)d_in[5];
    // d_in[6] = b2: dropped (softmax shift-invariant)
    float* out = (float*)d_out;

    float* Ek = (float*)d_ws;                          // B*H*NK floats
    float* eq = Ek + (size_t)B * H * NK;               // B*NQ*H floats
    unsigned int* ctr = (unsigned int*)(eq + (size_t)B * NQ * H);

    hipMemsetAsync(ctr, 0, sizeof(unsigned int), stream);   // capture-legal memset node
    fused_kernel<<<NBLOCKS, 512, 0, stream>>>(keys, queries, Wk, Wq, b1, w2,
                                              Ek, eq, ctr, out);
}

// Round 14
// 48.144 us; speedup vs baseline: 1.4428x; 1.4428x over previous
//
#include <hip/hip_runtime.h>

#define B 4
#define NQ 512
#define NK 512
#define D 128
#define H 32
#define G 4                              // queries per block
#define PS 2.8853900817779268f           // 2*log2(e)
#define NBLOCKS 512

__device__ __forceinline__ float rcp_f(float x)  { return __builtin_amdgcn_rcpf(x); }
__device__ __forceinline__ float exp2_f(float x) { return __builtin_amdgcn_exp2f(x); }

__device__ __forceinline__ void fma4(float4& a, const float4& v, float s) {
    a.x = fmaf(s, v.x, a.x);
    a.y = fmaf(s, v.y, a.y);
    a.z = fmaf(s, v.z, a.z);
    a.w = fmaf(s, v.w, a.w);
}

// Agent-scope (device-coherent) accesses: compile to global_load/store ... sc1,
// which operate at the LLC (cross-XCD coherence point). No L2 flush needed.
__device__ __forceinline__ void store_llc(float* p, float v) {
    __hip_atomic_store(p, v, __ATOMIC_RELAXED, __HIP_MEMORY_SCOPE_AGENT);
}
__device__ __forceinline__ float load_llc(const float* p) {
    return __hip_atomic_load(p, __ATOMIC_RELAXED, __HIP_MEMORY_SCOPE_AGENT);
}

// Single fused kernel, one block per (b, 4-query tile).
// Phase A: block computes its own eq rows (LDS-local, never shared) and its
//          owned 4 keys' Ek columns (sc1 stores to LLC; each Ek elem written once).
// Barrier: vmcnt-drained sc1 stores + relaxed agent atomic counter. NO fences.
// Phase 1/2: r11 attend body; eq from LDS, Ek via sc1 loads.
__global__ __launch_bounds__(512, 6) void fused_kernel(
    const float* __restrict__ keys, const float* __restrict__ queries,
    const float* __restrict__ Wk, const float* __restrict__ Wq,
    const float* __restrict__ b1, const float* __restrict__ w2,
    float* __restrict__ Ek,       // [B][H][NK] ws, LLC-coherent
    unsigned int* __restrict__ ctr,
    float* __restrict__ outp)
{
    __shared__ float exw[NK][G];      // 8 KB   normalized weights
    __shared__ float accm[16][G][D];  // 32 KB  ph2 partials; head doubles as red[8][G]
    __shared__ float eq_s[G][H];      // this block's query projections
    float* red = &accm[0][0][0];

    const int tid = threadIdx.x;
    const int bid = blockIdx.x;
    const int b   = bid >> 7;
    const int t   = bid & 127;
    const int q0  = t * G;
    const int k0  = t * 4;

    // ================= phase A ==============================================
    // task layout: tid = g*128 + h*4 + qtr ; each task: 32-MAC quarter-dot,
    // combined over qtr via shfl_xor(1,2).
    const int qtr = tid & 3;
    const int h   = (tid >> 2) & 31;
    const int g   = tid >> 7;
    {   // eq for query q0+g, head h
        const float4* x4 = reinterpret_cast<const float4*>(
            queries + ((size_t)b * NQ + q0 + g) * D + qtr * 32);
        const float* wq = Wq + (qtr * 32) * H + h;
        float a0 = 0.f, a1 = 0.f, a2 = 0.f, a3 = 0.f;
        #pragma unroll
        for (int i = 0; i < 8; ++i) {
            float4 v = x4[i];
            a0 = fmaf(v.x, wq[(4 * i + 0) * H], a0);
            a1 = fmaf(v.y, wq[(4 * i + 1) * H], a1);
            a2 = fmaf(v.z, wq[(4 * i + 2) * H], a2);
            a3 = fmaf(v.w, wq[(4 * i + 3) * H], a3);
        }
        float acc = (a0 + a1) + (a2 + a3);
        acc += __shfl_xor(acc, 1);
        acc += __shfl_xor(acc, 2);
        if (qtr == 0) eq_s[g][h] = exp2_f(acc * PS);
    }
    {   // Ek for key k0+g, head h (this block owns keys k0..k0+3)
        const float4* x4 = reinterpret_cast<const float4*>(
            keys + ((size_t)b * NK + k0 + g) * D + qtr * 32);
        const float* wk = Wk + (qtr * 32) * H + h;
        float a0 = 0.f, a1 = 0.f, a2 = 0.f, a3 = 0.f;
        #pragma unroll
        for (int i = 0; i < 8; ++i) {
            float4 v = x4[i];
            a0 = fmaf(v.x, wk[(4 * i + 0) * H], a0);
            a1 = fmaf(v.y, wk[(4 * i + 1) * H], a1);
            a2 = fmaf(v.z, wk[(4 * i + 2) * H], a2);
            a3 = fmaf(v.w, wk[(4 * i + 3) * H], a3);
        }
        float acc = (a0 + a1) + (a2 + a3);
        acc += __shfl_xor(acc, 1);
        acc += __shfl_xor(acc, 2);
        if (qtr == 0)
            store_llc(&Ek[((size_t)b * H + h) * NK + (k0 + g)],
                      exp2_f((acc + b1[h]) * PS));
    }
    __syncthreads();   // vmcnt(0): sc1 stores acked at LLC; eq_s visible

    // ================= grid barrier (counter only, no cache maintenance) ====
    if (tid == 0) {
        __hip_atomic_fetch_add(ctr, 1u, __ATOMIC_RELAXED, __HIP_MEMORY_SCOPE_AGENT);
        while (__hip_atomic_load(ctr, __ATOMIC_RELAXED, __HIP_MEMORY_SCOPE_AGENT) < NBLOCKS)
            __builtin_amdgcn_s_sleep(2);
    }
    __syncthreads();

    // ================= phase 1: logits for key k = tid, queries q0..q0+3 ====
    float acc[G];
    #pragma unroll
    for (int gg = 0; gg < G; ++gg) acc[gg] = 0.f;
    const float* Ekc = Ek + (size_t)b * H * NK + tid;      // column base (per-lane)

    #pragma unroll
    for (int h4 = 0; h4 < H; h4 += 4) {
        const float ek0 = load_llc(&Ekc[(h4 + 0) * NK]);   // coalesced sc1 loads
        const float ek1 = load_llc(&Ekc[(h4 + 1) * NK]);
        const float ek2 = load_llc(&Ekc[(h4 + 2) * NK]);
        const float ek3 = load_llc(&Ekc[(h4 + 3) * NK]);
        const float w0 = w2[h4 + 0];            // uniform const -> s_load
        const float w1 = w2[h4 + 1];
        const float wc = w2[h4 + 2];
        const float w3 = w2[h4 + 3];
        #pragma unroll
        for (int gg = 0; gg < G; ++gg) {
            const float4 eqv = *reinterpret_cast<const float4*>(&eq_s[gg][h4]); // b128 broadcast
            const float d0 = fmaf(eqv.x, ek0, 1.f);
            const float d1 = fmaf(eqv.y, ek1, 1.f);
            const float d2 = fmaf(eqv.z, ek2, 1.f);
            const float d3 = fmaf(eqv.w, ek3, 1.f);
            const float nab = fmaf(w1, d0, w0 * d1);
            const float ncd = fmaf(w3, d2, wc * d3);
            const float dab = d0 * d1;
            const float dcd = d2 * d3;
            const float n4  = fmaf(nab, dcd, ncd * dab);
            const float d4  = dab * dcd;
            acc[gg] = fmaf(n4, rcp_f(d4), acc[gg]);        // ONE rcp per 4 h's
        }
    }
    // exponent = -PS*acc (const dropped; |exponent| <= 16.3 -> no max pass)
    float e0 = exp2_f(-PS * acc[0]);
    float e1 = exp2_f(-PS * acc[1]);
    float e2 = exp2_f(-PS * acc[2]);
    float e3 = exp2_f(-PS * acc[3]);

    // block sum over k (red aliases accm)
    float s0 = e0, s1 = e1, s2 = e2, s3 = e3;
    #pragma unroll
    for (int off = 32; off; off >>= 1) {
        s0 += __shfl_xor(s0, off);
        s1 += __shfl_xor(s1, off);
        s2 += __shfl_xor(s2, off);
        s3 += __shfl_xor(s3, off);
    }
    if ((tid & 63) == 0)
        *reinterpret_cast<float4*>(red + (tid >> 6) * G) = float4{s0, s1, s2, s3};
    __syncthreads();
    float4 sum = {0.f, 0.f, 0.f, 0.f};
    #pragma unroll
    for (int p = 0; p < 8; ++p) {
        const float4 v = *reinterpret_cast<const float4*>(red + p * G);
        sum.x += v.x; sum.y += v.y; sum.z += v.z; sum.w += v.w;
    }
    *reinterpret_cast<float4*>(&exw[tid][0]) =
        float4{e0 * rcp_f(sum.x), e1 * rcp_f(sum.y),
               e2 * rcp_f(sum.z), e3 * rcp_f(sum.w)};
    __syncthreads();                  // red reads done -> accm reusable

    // ================= phase 2: context =====================================
    const int dg = tid & 31;
    const int kp = tid >> 5;
    const float4* k4 = reinterpret_cast<const float4*>(
        keys + ((size_t)b * NK + kp * 32) * D) + dg;
    float4 a0 = {0,0,0,0}, a1 = a0, a2 = a0, a3 = a0;
    #pragma unroll 8
    for (int kk = 0; kk < 32; ++kk) {
        const float4 ev = *reinterpret_cast<const float4*>(&exw[kp * 32 + kk][0]);
        const float4 kv = k4[(size_t)kk * (D / 4)];
        fma4(a0, kv, ev.x);
        fma4(a1, kv, ev.y);
        fma4(a2, kv, ev.z);
        fma4(a3, kv, ev.w);
    }
    *reinterpret_cast<float4*>(&accm[kp][0][4 * dg]) = a0;
    *reinterpret_cast<float4*>(&accm[kp][1][4 * dg]) = a1;
    *reinterpret_cast<float4*>(&accm[kp][2][4 * dg]) = a2;
    *reinterpret_cast<float4*>(&accm[kp][3][4 * dg]) = a3;
    __syncthreads();

    const int gg = tid >> 7;
    const int d  = tid & 127;
    float r = 0.f;
    #pragma unroll
    for (int p = 0; p < 16; ++p) r += accm[p][gg][d];
    outp[((size_t)b * NQ + q0 + gg) * D + d] = r;
}

extern "C" void kernel_launch(void* const* d_in, const int* in_sizes, int n_in,
                              void* d_out, int out_size, void* d_ws, size_t ws_size,
                              hipStream_t stream) {
    const float* keys    = (const float*)d_in[0];
    const float* queries = (const float*)d_in[1];
    const float* Wk      = (const float*)d_in[2];
    const float* Wq      = (const float*)d_in[3];
    const float* b1      = (const float*)d_in[4];
    const float* w2      = (const float*)d_in[5];
    // d_in[6] = b2: dropped (softmax shift-invariant)
    float* out = (float*)d_out;

    float* Ek = (float*)d_ws;                          // B*H*NK floats
    unsigned int* ctr = (unsigned int*)(Ek + (size_t)B * H * NK);

    hipMemsetAsync(ctr, 0, sizeof(unsigned int), stream);   // capture-legal
    fused_kernel<<<NBLOCKS, 512, 0, stream>>>(keys, queries, Wk, Wq, b1, w2,
                                              Ek, ctr, out);
}

// Round 15
// 20.103 us; speedup vs baseline: 3.4554x; 2.3949x over previous
//
#include <hip/hip_runtime.h>

#define B 4
#define NQ 512
#define NK 512
#define D 128
#define H 32
#define G 4                              // queries per attend block
#define PS 2.8853900817779268f           // 2*log2(e)

__device__ __forceinline__ float rcp_f(float x)  { return __builtin_amdgcn_rcpf(x); }
__device__ __forceinline__ float exp2_f(float x) { return __builtin_amdgcn_exp2f(x); }

__device__ __forceinline__ void fma4(float4& a, const float4& v, float s) {
    a.x = fmaf(s, v.x, a.x);
    a.y = fmaf(s, v.y, a.y);
    a.z = fmaf(s, v.z, a.z);
    a.w = fmaf(s, v.w, a.w);
}

// Ek[b][h][k] = exp2(PS*(keys[b,k,:].Wk[:,h] + b1[h]))   (transposed)
// eq[b][q][h] = exp2(PS*(queries[b,q,:].Wq[:,h]))
__global__ __launch_bounds__(256) void proj_kernel(
    const float* __restrict__ keys, const float* __restrict__ queries,
    const float* __restrict__ Wk, const float* __restrict__ Wq,
    const float* __restrict__ b1,
    float* __restrict__ Ek, float* __restrict__ eq)
{
    __shared__ float xs[8][D];
    const int tid = threadIdx.x;
    const int r0 = blockIdx.x * 8;
    const bool is_q = (r0 >= B * NK);
    const float* __restrict__ X = is_q ? (queries + (size_t)(r0 - B * NK) * D)
                                       : (keys + (size_t)r0 * D);
    const float* __restrict__ W = is_q ? Wq : Wk;

    reinterpret_cast<float4*>(&xs[0][0])[tid] =
        reinterpret_cast<const float4*>(X)[tid];
    __syncthreads();

    const int lr = tid >> 5;
    const int h  = tid & 31;
    float a0 = 0.f, a1 = 0.f, a2 = 0.f, a3 = 0.f;
    const float4* x4 = reinterpret_cast<const float4*>(&xs[lr][0]);
    #pragma unroll
    for (int i = 0; i < D / 4; ++i) {
        float4 v = x4[i];
        a0 = fmaf(v.x, W[(4 * i + 0) * H + h], a0);
        a1 = fmaf(v.y, W[(4 * i + 1) * H + h], a1);
        a2 = fmaf(v.z, W[(4 * i + 2) * H + h], a2);
        a3 = fmaf(v.w, W[(4 * i + 3) * H + h], a3);
    }
    float acc = (a0 + a1) + (a2 + a3);
    if (is_q) {
        const int rq = r0 - B * NK + lr;
        eq[(size_t)rq * H + h] = exp2_f(acc * PS);
    } else {
        const int r = r0 + lr;
        const int b = r >> 9;
        const int k = r & (NK - 1);
        Ek[((size_t)b * H + h) * NK + k] = exp2_f((acc + b1[h]) * PS);
    }
}

// One block per (b, G=4 queries). 512 threads. r11 math; NEW: deep register
// prefetch — ph1 issues all 32 Ek loads before computing (one latency wait,
// not 8), ph2 double-buffers keys 8-deep — to hide cold-miss latency.
__global__ __launch_bounds__(512, 4) void attend_kernel(
    const float* __restrict__ keys,
    const float* __restrict__ Ek,     // [B][H][NK]
    const float* __restrict__ eq,     // [B][NQ][H]
    const float* __restrict__ w2,
    float* __restrict__ outp)
{
    __shared__ float exw[NK][G];      // 8 KB   normalized weights, [k][g]
    __shared__ float accm[16][G][D];  // 32 KB  ph2 partials; head doubles as red[8][G]
    float* red = &accm[0][0][0];

    const int tid = threadIdx.x;
    const int b   = blockIdx.x >> 7;
    const int q0  = (blockIdx.x & 127) * G;

    // ---- phase 1: prefetch ALL 32 Ek column values (independent loads) ----
    const float* Ekc = Ek + (size_t)b * H * NK + tid;
    float ek[H];
    #pragma unroll
    for (int h = 0; h < H; ++h) ek[h] = Ekc[h * NK];   // 32 outstanding b32 loads

    const float* eqb = eq + ((size_t)b * NQ + q0) * H;   // uniform -> s_load
    float acc[G];
    #pragma unroll
    for (int g = 0; g < G; ++g) acc[g] = 0.f;

    #pragma unroll
    for (int h4 = 0; h4 < H; h4 += 4) {
        const float w0 = w2[h4 + 0];            // scalar loads
        const float w1 = w2[h4 + 1];
        const float wc = w2[h4 + 2];
        const float w3 = w2[h4 + 3];
        #pragma unroll
        for (int g = 0; g < G; ++g) {
            const float d0 = fmaf(eqb[g * H + h4 + 0], ek[h4 + 0], 1.f);
            const float d1 = fmaf(eqb[g * H + h4 + 1], ek[h4 + 1], 1.f);
            const float d2 = fmaf(eqb[g * H + h4 + 2], ek[h4 + 2], 1.f);
            const float d3 = fmaf(eqb[g * H + h4 + 3], ek[h4 + 3], 1.f);
            const float nab = fmaf(w1, d0, w0 * d1);
            const float ncd = fmaf(w3, d2, wc * d3);
            const float dab = d0 * d1;
            const float dcd = d2 * d3;
            const float n4  = fmaf(nab, dcd, ncd * dab);
            const float d4  = dab * dcd;
            acc[g] = fmaf(n4, rcp_f(d4), acc[g]);      // ONE rcp per 4 h's
        }
    }
    // exponent = -PS*acc (const dropped; |exponent| <= 16.3 -> no max pass)
    float e0 = exp2_f(-PS * acc[0]);
    float e1 = exp2_f(-PS * acc[1]);
    float e2 = exp2_f(-PS * acc[2]);
    float e3 = exp2_f(-PS * acc[3]);

    // ---- block sum over k (red aliases accm) ----
    float s0 = e0, s1 = e1, s2 = e2, s3 = e3;
    #pragma unroll
    for (int off = 32; off; off >>= 1) {
        s0 += __shfl_xor(s0, off);
        s1 += __shfl_xor(s1, off);
        s2 += __shfl_xor(s2, off);
        s3 += __shfl_xor(s3, off);
    }
    if ((tid & 63) == 0)
        *reinterpret_cast<float4*>(red + (tid >> 6) * G) = float4{s0, s1, s2, s3};
    __syncthreads();
    float4 sum = {0.f, 0.f, 0.f, 0.f};
    #pragma unroll
    for (int p = 0; p < 8; ++p) {
        const float4 v = *reinterpret_cast<const float4*>(red + p * G);  // broadcast
        sum.x += v.x; sum.y += v.y; sum.z += v.z; sum.w += v.w;
    }
    *reinterpret_cast<float4*>(&exw[tid][0]) =
        float4{e0 * rcp_f(sum.x), e1 * rcp_f(sum.y),
               e2 * rcp_f(sum.z), e3 * rcp_f(sum.w)};
    __syncthreads();    // red reads done -> accm may be overwritten in ph2

    // ---- phase 2: context, keys double-buffered 8-deep ----
    const int dg = tid & 31;
    const int kp = tid >> 5;
    const float4* k4 = reinterpret_cast<const float4*>(
        keys + ((size_t)b * NK + kp * 32) * D) + dg;
    float4 a0 = {0,0,0,0}, a1 = a0, a2 = a0, a3 = a0;

    float4 kbA[8], kbB[8];
    #pragma unroll
    for (int j = 0; j < 8; ++j) kbA[j] = k4[(size_t)j * (D / 4)];   // chunk 0
    #pragma unroll
    for (int c = 0; c < 4; ++c) {
        float4* cur = (c & 1) ? kbB : kbA;
        float4* nxt = (c & 1) ? kbA : kbB;
        if (c < 3) {
            #pragma unroll
            for (int j = 0; j < 8; ++j)
                nxt[j] = k4[(size_t)((c + 1) * 8 + j) * (D / 4)];   // issue next chunk
        }
        #pragma unroll
        for (int j = 0; j < 8; ++j) {
            const int kk = c * 8 + j;
            const float4 ev = *reinterpret_cast<const float4*>(&exw[kp * 32 + kk][0]);
            fma4(a0, cur[j], ev.x);
            fma4(a1, cur[j], ev.y);
            fma4(a2, cur[j], ev.z);
            fma4(a3, cur[j], ev.w);
        }
    }
    *reinterpret_cast<float4*>(&accm[kp][0][4 * dg]) = a0;
    *reinterpret_cast<float4*>(&accm[kp][1][4 * dg]) = a1;
    *reinterpret_cast<float4*>(&accm[kp][2][4 * dg]) = a2;
    *reinterpret_cast<float4*>(&accm[kp][3][4 * dg]) = a3;
    __syncthreads();

    // ---- reduce 16 partitions; thread t -> output (g,d) ----
    const int g = tid >> 7;
    const int d = tid & 127;
    float r = 0.f;
    #pragma unroll
    for (int p = 0; p < 16; ++p) r += accm[p][g][d];
    outp[((size_t)b * NQ + q0 + g) * D + d] = r;
}

extern "C" void kernel_launch(void* const* d_in, const int* in_sizes, int n_in,
                              void* d_out, int out_size, void* d_ws, size_t ws_size,
                              hipStream_t stream) {
    const float* keys    = (const float*)d_in[0];
    const float* queries = (const float*)d_in[1];
    const float* Wk      = (const float*)d_in[2];
    const float* Wq      = (const float*)d_in[3];
    const float* b1      = (const float*)d_in[4];
    const float* w2      = (const float*)d_in[5];
    // d_in[6] = b2: dropped (softmax shift-invariant)
    float* out = (float*)d_out;

    float* Ek = (float*)d_ws;                    // B*H*NK floats (transposed)
    float* eq = Ek + (size_t)B * H * NK;         // B*NQ*H floats

    const int proj_blocks = (B * NK + B * NQ) / 8;   // 512
    proj_kernel<<<proj_blocks, 256, 0, stream>>>(keys, queries, Wk, Wq, b1, Ek, eq);
    attend_kernel<<<B * NQ / G, 512, 0, stream>>>(keys, Ek, eq, w2, out);
}